// Round 13
// baseline (163.751 us; speedup 1.0000x reference)
//
#include <hip/hip_runtime.h>
#include <math.h>

#define T_TOK 8192
#define HDIM 4096
#define NSLOT 128
#define KRET 4
#define TOPK 2048
#define ALPHA 0.1f
#define SEGS 16      // token segments
#define CHUNKS 64    // d-chunks of 64 floats (64*64=4096)

// ---------------- Kernel 1: per-token importance (+ zero rank) ----------------
__global__ __launch_bounds__(256) void importance_kernel(
    const float* __restrict__ h, const float* __restrict__ attn,
    const float* __restrict__ W, const float* __restrict__ b,
    float* __restrict__ imp, int* __restrict__ rank)
{
    const int wid  = threadIdx.x >> 6;
    const int lane = threadIdx.x & 63;
    const int t = blockIdx.x * 4 + wid;
    const float4* hv = reinterpret_cast<const float4*>(h + (size_t)t * HDIM);
    const float4* Wv = reinterpret_cast<const float4*>(W);
    float sumsq = 0.f, dot = 0.f;
    #pragma unroll 4
    for (int i = 0; i < 16; i++) {
        float4 x = hv[lane + i * 64];
        float4 w = Wv[lane + i * 64];
        sumsq += x.x * x.x + x.y * x.y + x.z * x.z + x.w * x.w;
        dot   += x.x * w.x + x.y * w.y + x.z * w.z + x.w * w.w;
    }
    #pragma unroll
    for (int off = 32; off > 0; off >>= 1) {
        sumsq += __shfl_down(sumsq, off);
        dot   += __shfl_down(dot, off);
    }
    if (lane == 0) {
        float mag = sqrtf(sumsq);
        float ent = 0.f;
        #pragma unroll
        for (int k = 0; k < KRET; k++) {
            float a = attn[t * KRET + k];
            ent -= a * logf(a + 1e-8f);
        }
        float surprise = ent / logf(4.0f);
        float score = dot + b[0];
        float sig = 1.0f / (1.0f + expf(-score));
        imp[t] = mag * (1.0f + surprise) + sig;
        rank[t] = 0;  // zero for rank_kernel (stream-ordered, replay-safe)
    }
}

// ---------------- Kernel 2: partial rank count, 2-D grid (R4, proven) --------
__global__ __launch_bounds__(256) void rank_kernel(
    const float* __restrict__ imp, int* __restrict__ rank)
{
    const int cb = blockIdx.x & 31;   // candidate block
    const int sl = blockIdx.x >> 5;   // compare slice
    __shared__ float tile[256];
    const int base = sl * 256;
    tile[threadIdx.x] = imp[base + threadIdx.x];
    __syncthreads();
    const int t = cb * 256 + threadIdx.x;
    const float mine = imp[t];
    int r = 0;
    #pragma unroll 8
    for (int i = 0; i < 256; i++) {
        float v = tile[i];
        int s = base + i;
        // jax.lax.top_k tie-break: higher value first, then lower index
        r += (v > mine) || (v == mine && s < t);
    }
    if (r) atomicAdd(&rank[t], r);
}

// ---------------- Kernel 3: scatter-accumulate partial sums -----------------
// grid = 16 segs x 64 chunks, 128 threads (2 waves). Each selected h-row is
// read ONCE per chunk (32 MB total vs 130 MB gather). Wave-private LDS
// accumulators -> fixed order -> deterministic, zero atomics.
__global__ __launch_bounds__(128) void scatter_kernel(
    const float* __restrict__ h, const int* __restrict__ rank,
    const int* __restrict__ si, float* __restrict__ partial,
    int* __restrict__ pcnt)
{
    const int chunk = blockIdx.x & 63;
    const int seg   = blockIdx.x >> 6;   // 0..15
    const int tid = threadIdx.x;
    const int w = tid >> 6, lane = tid & 63;

    __shared__ float s_acc[2][NSLOT * 64];  // 64 KB, wave-private halves
    __shared__ int   s_tok[2][256];
    __shared__ int   s_cnt[2][NSLOT];

    float* acc = s_acc[w];
    for (int i = tid; i < 2 * NSLOT * 64; i += 128) s_acc[0][i] = 0.f;
    for (int i = tid; i < 2 * NSLOT; i += 128) s_cnt[0][i] = 0;
    __syncthreads();

    // Phase A (lane = token): ballot-compact this wave's selected tokens
    const int tbase = seg * 512 + w * 256;
    int n = 0;
    #pragma unroll
    for (int it = 0; it < 4; it++) {
        const int t = tbase + it * 64 + lane;
        bool sel = rank[t] < TOPK;
        unsigned long long bal = __ballot(sel);
        if (sel) {
            int pos = n + (int)__popcll(bal & ((1ull << lane) - 1ull));
            s_tok[w][pos] = t;
        }
        n += (int)__popcll(bal);
    }

    // Phase B (lane = d-element): accumulate each selected row once
    const int4* si4 = reinterpret_cast<const int4*>(si);
    const int dbase = chunk * 64 + lane;
    for (int i = 0; i < n; i++) {
        const int t = s_tok[w][i];          // LDS broadcast (wave-uniform)
        const int4 s4 = si4[t];             // uniform address load
        const float x = h[(size_t)t * HDIM + dbase];
        bool dy = (s4.y != s4.x);
        bool dz = (s4.z != s4.x) && (s4.z != s4.y);
        bool dw = (s4.w != s4.x) && (s4.w != s4.y) && (s4.w != s4.z);
        acc[s4.x * 64 + lane] += x;
        if (dy) acc[s4.y * 64 + lane] += x;
        if (dz) acc[s4.z * 64 + lane] += x;
        if (dw) acc[s4.w * 64 + lane] += x;
        if (lane == 0) {
            s_cnt[w][s4.x]++;
            if (dy) s_cnt[w][s4.y]++;
            if (dz) s_cnt[w][s4.z]++;
            if (dw) s_cnt[w][s4.w]++;
        }
    }
    __syncthreads();

    // Block combine (wave0 + wave1, fixed order) -> partial[seg][slot][chunk]
    for (int i = tid; i < NSLOT * 64; i += 128) {
        const int slot = i >> 6;
        const int d = i & 63;
        partial[((size_t)(seg * NSLOT + slot)) * HDIM + chunk * 64 + d] =
            s_acc[0][i] + s_acc[1][i];
    }
    if (chunk == 0 && tid < NSLOT)
        pcnt[seg * NSLOT + tid] = s_cnt[0][tid] + s_cnt[1][tid];
}

// ---------------- Kernel 4: combine partials + EMA + write output ----------
__global__ __launch_bounds__(256) void combine_kernel(
    const float* __restrict__ partial, const int* __restrict__ pcnt,
    const float* __restrict__ mem, float* __restrict__ out)
{
    const int slot = blockIdx.x >> 2;
    const int q = blockIdx.x & 3;
    const int dbase = q * 1024 + threadIdx.x * 4;

    int cnt = 0;
    float4 s = make_float4(0.f, 0.f, 0.f, 0.f);
    #pragma unroll
    for (int seg = 0; seg < SEGS; seg++) {
        cnt += pcnt[seg * NSLOT + slot];
        float4 p = *reinterpret_cast<const float4*>(
            partial + ((size_t)(seg * NSLOT + slot)) * HDIM + dbase);
        s.x += p.x; s.y += p.y; s.z += p.z; s.w += p.w;
    }

    const size_t o = (size_t)slot * HDIM + dbase;
    float4 cur = *reinterpret_cast<const float4*>(mem + o);
    float4 r;
    if (cnt > 0) {
        float inv = 1.0f / (float)cnt;
        r.x = ALPHA * (s.x * inv) + (1.f - ALPHA) * cur.x;
        r.y = ALPHA * (s.y * inv) + (1.f - ALPHA) * cur.y;
        r.z = ALPHA * (s.z * inv) + (1.f - ALPHA) * cur.z;
        r.w = ALPHA * (s.w * inv) + (1.f - ALPHA) * cur.w;
    } else {
        r = cur;
    }
    *reinterpret_cast<float4*>(out + o) = r;
}

extern "C" void kernel_launch(void* const* d_in, const int* in_sizes, int n_in,
                              void* d_out, int out_size, void* d_ws, size_t ws_size,
                              hipStream_t stream) {
    const float* h    = (const float*)d_in[0];  // [8192, 4096]
    const float* attn = (const float*)d_in[1];  // [8192, 4]
    const int*   si   = (const int*)d_in[2];    // [8192, 4]
    const float* mem  = (const float*)d_in[3];  // [1, 128, 4096]
    const float* W    = (const float*)d_in[4];  // [1, 4096]
    const float* b    = (const float*)d_in[5];  // [1]
    float* out = (float*)d_out;                 // [1, 128, 4096]

    char* ws = (char*)d_ws;
    float* imp     = (float*)(ws);             // 8192 f32
    int*   rank    = (int*)(ws + 32768);       // 8192 i32
    int*   pcnt    = (int*)(ws + 65536);       // 16 x 128 i32
    float* partial = (float*)(ws + 2097152);   // 16 x 128 x 4096 f32 (32 MB)

    importance_kernel<<<T_TOK / 4, 256, 0, stream>>>(h, attn, W, b, imp, rank);
    rank_kernel<<<1024, 256, 0, stream>>>(imp, rank);
    scatter_kernel<<<SEGS * CHUNKS, 128, 0, stream>>>(h, rank, si, partial, pcnt);
    combine_kernel<<<NSLOT * 4, 256, 0, stream>>>(partial, pcnt, mem, out);
}